// Round 2
// baseline (503.089 us; speedup 1.0000x reference)
//
#include <hip/hip_runtime.h>
#include <math.h>

// Problem constants (from reference): B=4, C_in=C_out=256, H=W=256, 4 levels.
// k per level: L0=1, L1=4, L2=8, L3=19  -> 32 tokens/batch.
#define BB 4
#define CC 256
#define HH 256
#define WW 256

// d_out layout (floats):
//   out        @ 0          size 4*256*256*256 = 67108864
//   sparse_seq @ 67108864   size 4*32*256      = 32768
//   all_coords @ 67141632   size 4*32*4        = 512
//   sparsity   @ 67142144   size 1
//
// ws layout (floats):
//   pyr3 [B][C][64] @ 0
//   pyr2 [B][C][16] @ 65536
//   pyr1 [B][C][4]  @ 81920
//   pyr0 [B][C][1]  @ 86016
//   tokens (int)  [B][32][2] @ float-offset 87040  (256 ints)
//   val_id (int)  [B][64]    @ after tokens        (256 ints)

// ---------------- Kernel A: 32x32 block max (pyr3) ----------------
// grid = B*C*8 (one block per (b,c,row-block)), 256 threads.
__global__ __launch_bounds__(256) void pool3_kernel(
    const float* __restrict__ x, float* __restrict__ pyr3) {
  int blk = blockIdx.x;
  int by = blk & 7;            // row block 0..7
  int c  = (blk >> 3) & 255;
  int b  = blk >> 11;
  const float4* src =
      (const float4*)(x + ((size_t)(b * CC + c) * HH + by * 32) * WW);
  int tid = threadIdx.x;
  float m = -INFINITY;
#pragma unroll
  for (int it = 0; it < 8; ++it) {
    float4 v = src[it * 256 + tid];  // coalesced 4 KB per iteration
    m = fmaxf(m, fmaxf(fmaxf(v.x, v.y), fmaxf(v.z, v.w)));
  }
  // thread's column-block is fixed: cb = (tid&63)>>3
  __shared__ float lds[256];
  lds[tid] = m;
  __syncthreads();
  if (tid < 8) {  // tid == cb
    float mm = -INFINITY;
#pragma unroll
    for (int wv = 0; wv < 4; ++wv)
#pragma unroll
      for (int j = 0; j < 8; ++j)
        mm = fmaxf(mm, lds[wv * 64 + tid * 8 + j]);
    pyr3[((b * CC + c) * 8 + by) * 8 + tid] = mm;  // cell = by*8 + cb
  }
}

// ---------------- small helpers ----------------
__device__ __forceinline__ float blockSumAll(float v, float* red) {
  for (int off = 32; off; off >>= 1) v += __shfl_down(v, off, 64);
  __syncthreads();  // protect red from previous call's readers
  if ((threadIdx.x & 63) == 0) red[threadIdx.x >> 6] = v;
  __syncthreads();
  return red[0] + red[1] + red[2] + red[3];
}

// Wave-parallel stable top-k: lane n holds imp of cell n (lanes >= N hold
// -inf). Strict (>, then lower index) argmax == jax.lax.top_k tie order.
// Writes tokens+coords (lane 0) and per-cell selection position (lanes < N).
__device__ __forceinline__ void wave_topk(float imp, int N, int k, int g,
                                          int level, int base, int b, int lane,
                                          int* tokens, float* coords,
                                          int* posOut) {
  int pos = -1;
  float v = (lane < N) ? imp : -INFINITY;
  for (int t = 0; t < k; ++t) {
    float mv = v;
    int mi = lane;
    for (int off = 32; off; off >>= 1) {
      float ov = __shfl_xor(mv, off, 64);
      int oi = __shfl_xor(mi, off, 64);
      if (ov > mv || (ov == mv && oi < mi)) {
        mv = ov;
        mi = oi;
      }
    }
    if (lane == mi) {
      pos = t;
      v = -INFINITY;
    }
    if (lane == 0) {
      int s = base + t;
      tokens[(b * 32 + s) * 2 + 0] = level;
      tokens[(b * 32 + s) * 2 + 1] = mi;
      float inv = 1.0f / (float)g;
      coords[(b * 32 + s) * 4 + 0] = ((mi % g) + 0.5f) * inv;  // cx
      coords[(b * 32 + s) * 4 + 1] = ((mi / g) + 0.5f) * inv;  // cy
      coords[(b * 32 + s) * 4 + 2] = inv;
      coords[(b * 32 + s) * 4 + 3] = inv;
    }
  }
  if (lane < N) posOut[lane] = pos;
}

// ---------------- Kernel B: coarse pools + norms + topk + LUT ----------------
// grid = B, 256 threads.
__global__ __launch_bounds__(256) void levels_kernel(
    const float* __restrict__ pyr3, float* __restrict__ pyr2,
    float* __restrict__ pyr1, float* __restrict__ pyr0,
    int* __restrict__ tokens, int* __restrict__ val_id,
    float* __restrict__ coords, float* __restrict__ sparsity) {
  int b = blockIdx.x;
  int tid = threadIdx.x;
  int wave = tid >> 6, lane = tid & 63;

  // ---- phase 1: coarse pools, thread == channel ----
  {
    int c = tid;
    const float* p3 = pyr3 + (b * CC + c) * 64;
    float* q2 = pyr2 + (b * CC + c) * 16;
    float* q1 = pyr1 + (b * CC + c) * 4;
    float* q0 = pyr0 + (b * CC + c);
    float t2[16];
#pragma unroll
    for (int n = 0; n < 16; ++n) {
      int i = n >> 2, j = n & 3;
      t2[n] = fmaxf(
          fmaxf(p3[(2 * i) * 8 + 2 * j], p3[(2 * i) * 8 + 2 * j + 1]),
          fmaxf(p3[(2 * i + 1) * 8 + 2 * j], p3[(2 * i + 1) * 8 + 2 * j + 1]));
      q2[n] = t2[n];
    }
    float t1[4];
#pragma unroll
    for (int n = 0; n < 4; ++n) {
      int i = n >> 1, j = n & 1;
      t1[n] = fmaxf(fmaxf(t2[(2 * i) * 4 + 2 * j], t2[(2 * i) * 4 + 2 * j + 1]),
                    fmaxf(t2[(2 * i + 1) * 4 + 2 * j],
                          t2[(2 * i + 1) * 4 + 2 * j + 1]));
      q1[n] = t1[n];
    }
    q0[0] = fmaxf(fmaxf(t1[0], t1[1]), fmaxf(t1[2], t1[3]));
  }
  __syncthreads();  // q2/q1/q0 visible block-wide

  // ---- phase 2: L2 norms, wave == cell (cells 0..63 L3, 64..79 L2,
  //      80..83 L1, 84 L0) ----
  __shared__ float l2s[85];
  for (int m = wave; m < 85; m += 4) {
    const float* src;
    int n, N;
    if (m < 64) {
      src = pyr3; N = 64; n = m;
    } else if (m < 80) {
      src = pyr2; N = 16; n = m - 64;
    } else if (m < 84) {
      src = pyr1; N = 4; n = m - 80;
    } else {
      src = pyr0; N = 1; n = 0;
    }
    float s = 0.0f;
#pragma unroll
    for (int cc = 0; cc < 4; ++cc) {
      float v = src[(b * CC + cc * 64 + lane) * N + n];
      s = fmaf(v, v, s);
    }
#pragma unroll
    for (int off = 32; off; off >>= 1) s += __shfl_xor(s, off, 64);
    if (lane == 0) l2s[m] = sqrtf(s);
  }
  __syncthreads();

  // ---- phase 3+4: top-k per level + paint LUT, wave 0 only ----
  if (tid < 64) {
    __shared__ int posLds[84];  // pos3 @0..63, pos2 @64..79, pos1 @80..83
    // level 3: imp = l2
    wave_topk(l2s[lane], 64, 19, 8, 3, 13, b, lane, tokens, coords, posLds);
    // level 2: |l2 - parent(l3 @ (2i,2j))|
    {
      int i = lane >> 2, j = lane & 3;
      float imp =
          (lane < 16) ? fabsf(l2s[64 + lane] - l2s[16 * i + 2 * j]) : 0.0f;
      wave_topk(imp, 16, 8, 4, 2, 5, b, lane, tokens, coords, posLds + 64);
    }
    // level 1
    {
      int i = lane >> 1, j = lane & 1;
      float imp =
          (lane < 4) ? fabsf(l2s[80 + lane] - l2s[64 + 8 * i + 2 * j]) : 0.0f;
      wave_topk(imp, 4, 4, 2, 1, 1, b, lane, tokens, coords, posLds + 80);
    }
    // level 0
    {
      float imp = fabsf(l2s[84] - l2s[80]);
      int dummy;
      wave_topk(imp, 1, 1, 1, 0, 0, b, lane, tokens, coords, &dummy);
    }
    // paint LUT: finest kept level wins (level1 keeps all 4 -> covered)
    {
      int i = lane >> 3, j = lane & 7;
      int p3v = posLds[lane];
      int p2v = posLds[64 + (i >> 1) * 4 + (j >> 1)];
      int p1v = posLds[80 + (i >> 2) * 2 + (j >> 2)];
      int t = (p3v >= 0) ? 13 + p3v : ((p2v >= 0) ? 5 + p2v : 1 + p1v);
      val_id[b * 64 + lane] = t;
    }
    if (tid == 0 && b == 0) sparsity[0] = 32.0f / 65536.0f;
  }
}

// ---------------- Kernel C: LayerNorm + Linear per token ----------------
// grid = B*32, 256 threads (thread == output channel).
__global__ __launch_bounds__(256) void proj_kernel(
    const float* __restrict__ pyr3, const float* __restrict__ pyr2,
    const float* __restrict__ pyr1, const float* __restrict__ pyr0,
    const int* __restrict__ tokens, const float* __restrict__ ln_g,
    const float* __restrict__ ln_b, const float* __restrict__ w,
    const float* __restrict__ bias, float* __restrict__ sparse_out) {
  int blk = blockIdx.x;
  int b = blk >> 5, s = blk & 31;
  int tid = threadIdx.x;
  int level = tokens[(b * 32 + s) * 2 + 0];
  int cell = tokens[(b * 32 + s) * 2 + 1];
  const float* src;
  int N;
  if (level == 0) { src = pyr0; N = 1; }
  else if (level == 1) { src = pyr1; N = 4; }
  else if (level == 2) { src = pyr2; N = 16; }
  else { src = pyr3; N = 64; }
  float v = src[(b * CC + tid) * N + cell];

  __shared__ float red[4];
  __shared__ float kf[256];
  float mu = blockSumAll(v, red) * (1.0f / 256.0f);
  float d = v - mu;
  float var = blockSumAll(d * d, red) * (1.0f / 256.0f);
  float kfn = d / sqrtf(var + 1e-5f) * ln_g[tid] + ln_b[tid];
  kf[tid] = kfn;
  __syncthreads();
  float acc = bias[tid];
#pragma unroll 8
  for (int cc = 0; cc < 256; ++cc)
    acc = fmaf(kf[cc], w[cc * 256 + tid], acc);
  sparse_out[(b * 32 + s) * 256 + tid] = acc;
}

// ---------------- Kernel D: dense paint ----------------
// grid-stride over float4s of out.
__global__ __launch_bounds__(256) void fill_kernel(
    const float* __restrict__ sparse, const int* __restrict__ val_id,
    float4* __restrict__ out) {
  const int total = BB * CC * HH * (WW / 4);  // 16,777,216 float4
  for (int i = blockIdx.x * blockDim.x + threadIdx.x; i < total;
       i += gridDim.x * blockDim.x) {
    int b = i >> 22;
    int ch = (i >> 14) & 255;
    int h = (i >> 6) & 255;
    int w4 = i & 63;
    int cell = ((h >> 5) << 3) | (w4 >> 3);
    int tok = val_id[(b << 6) + cell];
    float v = sparse[((b * 32 + tok) << 8) + ch];
    out[i] = make_float4(v, v, v, v);
  }
}

extern "C" void kernel_launch(void* const* d_in, const int* in_sizes, int n_in,
                              void* d_out, int out_size, void* d_ws,
                              size_t ws_size, hipStream_t stream) {
  const float* x = (const float*)d_in[0];
  const float* ln_g = (const float*)d_in[1];
  const float* ln_b = (const float*)d_in[2];
  const float* w = (const float*)d_in[3];
  const float* bias = (const float*)d_in[4];

  float* out = (float*)d_out;
  float* sparse = out + (size_t)67108864;
  float* coords = sparse + 32768;
  float* sparsity = coords + 512;

  float* ws = (float*)d_ws;
  float* pyr3 = ws;
  float* pyr2 = ws + 65536;
  float* pyr1 = ws + 81920;
  float* pyr0 = ws + 86016;
  int* tokens = (int*)(ws + 87040);
  int* val_id = tokens + BB * 64;

  hipLaunchKernelGGL(pool3_kernel, dim3(BB * CC * 8), dim3(256), 0, stream, x,
                     pyr3);
  hipLaunchKernelGGL(levels_kernel, dim3(BB), dim3(256), 0, stream, pyr3, pyr2,
                     pyr1, pyr0, tokens, val_id, coords, sparsity);
  hipLaunchKernelGGL(proj_kernel, dim3(BB * 32), dim3(256), 0, stream, pyr3,
                     pyr2, pyr1, pyr0, tokens, ln_g, ln_b, w, bias, sparse);
  hipLaunchKernelGGL(fill_kernel, dim3(16384), dim3(256), 0, stream, sparse,
                     val_id, (float4*)out);
}

// Round 4
// 475.187 us; speedup vs baseline: 1.0587x; 1.0587x over previous
//
#include <hip/hip_runtime.h>
#include <math.h>

// Problem constants (from reference): B=4, C_in=C_out=256, H=W=256, 4 levels.
// k per level: L0=1, L1=4, L2=8, L3=19  -> 32 tokens/batch.
#define BB 4
#define CC 256
#define HH 256
#define WW 256

// native vector type for nontemporal builtins (HIP_vector_type is rejected)
typedef float floatx4 __attribute__((ext_vector_type(4)));

// d_out layout (floats):
//   out        @ 0          size 4*256*256*256 = 67108864
//   sparse_seq @ 67108864   size 4*32*256      = 32768
//   all_coords @ 67141632   size 4*32*4        = 512
//   sparsity   @ 67142144   size 1
//
// ws layout (floats):
//   pyr3 [B][C][64] @ 0
//   pyr2 [B][C][16] @ 65536
//   pyr1 [B][C][4]  @ 81920
//   pyr0 [B][C][1]  @ 86016
//   tokens (int)  [B][32][2] @ float-offset 87040  (256 ints)
//   val_id (int)  [B][64]    @ after tokens        (256 ints)

// ---------------- Kernel A: 32x32 block max (pyr3) ----------------
// grid = B*C*8 (one block per (b,c,row-block)), 256 threads.
__global__ __launch_bounds__(256) void pool3_kernel(
    const float* __restrict__ x, float* __restrict__ pyr3) {
  int blk = blockIdx.x;
  int by = blk & 7;            // row block 0..7
  int c  = (blk >> 3) & 255;
  int b  = blk >> 11;
  const floatx4* src =
      (const floatx4*)(x + ((size_t)(b * CC + c) * HH + by * 32) * WW);
  int tid = threadIdx.x;
  float m = -INFINITY;
#pragma unroll
  for (int it = 0; it < 8; ++it) {
    // single-use stream: non-temporal load, keep L2 for the rest
    floatx4 v = __builtin_nontemporal_load(&src[it * 256 + tid]);
    m = fmaxf(m, fmaxf(fmaxf(v.x, v.y), fmaxf(v.z, v.w)));
  }
  // thread's column-block is fixed: cb = (tid&63)>>3
  __shared__ float lds[256];
  lds[tid] = m;
  __syncthreads();
  if (tid < 8) {  // tid == cb
    float mm = -INFINITY;
#pragma unroll
    for (int wv = 0; wv < 4; ++wv)
#pragma unroll
      for (int j = 0; j < 8; ++j)
        mm = fmaxf(mm, lds[wv * 64 + tid * 8 + j]);
    pyr3[((b * CC + c) * 8 + by) * 8 + tid] = mm;  // cell = by*8 + cb
  }
}

// ---------------- small helpers ----------------
__device__ __forceinline__ float blockSumAll(float v, float* red) {
  for (int off = 32; off; off >>= 1) v += __shfl_down(v, off, 64);
  __syncthreads();  // protect red from previous call's readers
  if ((threadIdx.x & 63) == 0) red[threadIdx.x >> 6] = v;
  __syncthreads();
  return red[0] + red[1] + red[2] + red[3];
}

// Wave-parallel stable top-k: lane n holds imp of cell n (lanes >= N hold
// -inf). Strict (>, then lower index) argmax == jax.lax.top_k tie order.
// Writes tokens+coords (lane 0) and per-cell selection position (lanes < N).
__device__ __forceinline__ void wave_topk(float imp, int N, int k, int g,
                                          int level, int base, int b, int lane,
                                          int* tokens, float* coords,
                                          int* posOut) {
  int pos = -1;
  float v = (lane < N) ? imp : -INFINITY;
  for (int t = 0; t < k; ++t) {
    float mv = v;
    int mi = lane;
    for (int off = 32; off; off >>= 1) {
      float ov = __shfl_xor(mv, off, 64);
      int oi = __shfl_xor(mi, off, 64);
      if (ov > mv || (ov == mv && oi < mi)) {
        mv = ov;
        mi = oi;
      }
    }
    if (lane == mi) {
      pos = t;
      v = -INFINITY;
    }
    if (lane == 0) {
      int s = base + t;
      tokens[(b * 32 + s) * 2 + 0] = level;
      tokens[(b * 32 + s) * 2 + 1] = mi;
      float inv = 1.0f / (float)g;
      coords[(b * 32 + s) * 4 + 0] = ((mi % g) + 0.5f) * inv;  // cx
      coords[(b * 32 + s) * 4 + 1] = ((mi / g) + 0.5f) * inv;  // cy
      coords[(b * 32 + s) * 4 + 2] = inv;
      coords[(b * 32 + s) * 4 + 3] = inv;
    }
  }
  if (lane < N) posOut[lane] = pos;
}

// ---------------- Kernel B: coarse pools + norms + topk + LUT ----------------
// grid = B, 256 threads.
__global__ __launch_bounds__(256) void levels_kernel(
    const float* __restrict__ pyr3, float* __restrict__ pyr2,
    float* __restrict__ pyr1, float* __restrict__ pyr0,
    int* __restrict__ tokens, int* __restrict__ val_id,
    float* __restrict__ coords, float* __restrict__ sparsity) {
  int b = blockIdx.x;
  int tid = threadIdx.x;
  int wave = tid >> 6, lane = tid & 63;

  // ---- phase 1: coarse pools, thread == channel ----
  {
    int c = tid;
    const float* p3 = pyr3 + (b * CC + c) * 64;
    float* q2 = pyr2 + (b * CC + c) * 16;
    float* q1 = pyr1 + (b * CC + c) * 4;
    float* q0 = pyr0 + (b * CC + c);
    float t2[16];
#pragma unroll
    for (int n = 0; n < 16; ++n) {
      int i = n >> 2, j = n & 3;
      t2[n] = fmaxf(
          fmaxf(p3[(2 * i) * 8 + 2 * j], p3[(2 * i) * 8 + 2 * j + 1]),
          fmaxf(p3[(2 * i + 1) * 8 + 2 * j], p3[(2 * i + 1) * 8 + 2 * j + 1]));
      q2[n] = t2[n];
    }
    float t1[4];
#pragma unroll
    for (int n = 0; n < 4; ++n) {
      int i = n >> 1, j = n & 1;
      t1[n] = fmaxf(fmaxf(t2[(2 * i) * 4 + 2 * j], t2[(2 * i) * 4 + 2 * j + 1]),
                    fmaxf(t2[(2 * i + 1) * 4 + 2 * j],
                          t2[(2 * i + 1) * 4 + 2 * j + 1]));
      q1[n] = t1[n];
    }
    q0[0] = fmaxf(fmaxf(t1[0], t1[1]), fmaxf(t1[2], t1[3]));
  }
  __syncthreads();  // q2/q1/q0 visible block-wide

  // ---- phase 2: L2 norms, wave == cell (cells 0..63 L3, 64..79 L2,
  //      80..83 L1, 84 L0) ----
  __shared__ float l2s[85];
  for (int m = wave; m < 85; m += 4) {
    const float* src;
    int n, N;
    if (m < 64) {
      src = pyr3; N = 64; n = m;
    } else if (m < 80) {
      src = pyr2; N = 16; n = m - 64;
    } else if (m < 84) {
      src = pyr1; N = 4; n = m - 80;
    } else {
      src = pyr0; N = 1; n = 0;
    }
    float s = 0.0f;
#pragma unroll
    for (int cc = 0; cc < 4; ++cc) {
      float v = src[(b * CC + cc * 64 + lane) * N + n];
      s = fmaf(v, v, s);
    }
#pragma unroll
    for (int off = 32; off; off >>= 1) s += __shfl_xor(s, off, 64);
    if (lane == 0) l2s[m] = sqrtf(s);
  }
  __syncthreads();

  // ---- phase 3+4: top-k per level + paint LUT, wave 0 only ----
  if (tid < 64) {
    __shared__ int posLds[84];  // pos3 @0..63, pos2 @64..79, pos1 @80..83
    // level 3: imp = l2
    wave_topk(l2s[lane], 64, 19, 8, 3, 13, b, lane, tokens, coords, posLds);
    // level 2: |l2 - parent(l3 @ (2i,2j))|
    {
      int i = lane >> 2, j = lane & 3;
      float imp =
          (lane < 16) ? fabsf(l2s[64 + lane] - l2s[16 * i + 2 * j]) : 0.0f;
      wave_topk(imp, 16, 8, 4, 2, 5, b, lane, tokens, coords, posLds + 64);
    }
    // level 1
    {
      int i = lane >> 1, j = lane & 1;
      float imp =
          (lane < 4) ? fabsf(l2s[80 + lane] - l2s[64 + 8 * i + 2 * j]) : 0.0f;
      wave_topk(imp, 4, 4, 2, 1, 1, b, lane, tokens, coords, posLds + 80);
    }
    // level 0
    {
      float imp = fabsf(l2s[84] - l2s[80]);
      int dummy;
      wave_topk(imp, 1, 1, 1, 0, 0, b, lane, tokens, coords, &dummy);
    }
    // paint LUT: finest kept level wins (level1 keeps all 4 -> covered)
    {
      int i = lane >> 3, j = lane & 7;
      int p3v = posLds[lane];
      int p2v = posLds[64 + (i >> 1) * 4 + (j >> 1)];
      int p1v = posLds[80 + (i >> 2) * 2 + (j >> 2)];
      int t = (p3v >= 0) ? 13 + p3v : ((p2v >= 0) ? 5 + p2v : 1 + p1v);
      val_id[b * 64 + lane] = t;
    }
    if (tid == 0 && b == 0) sparsity[0] = 32.0f / 65536.0f;
  }
}

// ---------------- Kernel C: LayerNorm + Linear per token ----------------
// grid = B*32, 256 threads (thread == output channel).
__global__ __launch_bounds__(256) void proj_kernel(
    const float* __restrict__ pyr3, const float* __restrict__ pyr2,
    const float* __restrict__ pyr1, const float* __restrict__ pyr0,
    const int* __restrict__ tokens, const float* __restrict__ ln_g,
    const float* __restrict__ ln_b, const float* __restrict__ w,
    const float* __restrict__ bias, float* __restrict__ sparse_out) {
  int blk = blockIdx.x;
  int b = blk >> 5, s = blk & 31;
  int tid = threadIdx.x;
  int level = tokens[(b * 32 + s) * 2 + 0];
  int cell = tokens[(b * 32 + s) * 2 + 1];
  const float* src;
  int N;
  if (level == 0) { src = pyr0; N = 1; }
  else if (level == 1) { src = pyr1; N = 4; }
  else if (level == 2) { src = pyr2; N = 16; }
  else { src = pyr3; N = 64; }
  float v = src[(b * CC + tid) * N + cell];

  __shared__ float red[4];
  __shared__ float kf[256];
  float mu = blockSumAll(v, red) * (1.0f / 256.0f);
  float d = v - mu;
  float var = blockSumAll(d * d, red) * (1.0f / 256.0f);
  float kfn = d / sqrtf(var + 1e-5f) * ln_g[tid] + ln_b[tid];
  kf[tid] = kfn;
  __syncthreads();
  float acc = bias[tid];
#pragma unroll 8
  for (int cc = 0; cc < 256; ++cc)
    acc = fmaf(kf[cc], w[cc * 256 + tid], acc);
  sparse_out[(b * 32 + s) * 256 + tid] = acc;
}

// ---------------- Kernel D: dense paint ----------------
// grid-stride over float4s of out, non-temporal stores (write-only stream).
__global__ __launch_bounds__(256) void fill_kernel(
    const float* __restrict__ sparse, const int* __restrict__ val_id,
    floatx4* __restrict__ out) {
  const int total = BB * CC * HH * (WW / 4);  // 16,777,216 float4
  for (int i = blockIdx.x * blockDim.x + threadIdx.x; i < total;
       i += gridDim.x * blockDim.x) {
    int b = i >> 22;
    int ch = (i >> 14) & 255;
    int h = (i >> 6) & 255;
    int w4 = i & 63;
    int cell = ((h >> 5) << 3) | (w4 >> 3);
    int tok = val_id[(b << 6) + cell];
    float v = sparse[((b * 32 + tok) << 8) + ch];
    floatx4 val = {v, v, v, v};
    __builtin_nontemporal_store(val, &out[i]);
  }
}

extern "C" void kernel_launch(void* const* d_in, const int* in_sizes, int n_in,
                              void* d_out, int out_size, void* d_ws,
                              size_t ws_size, hipStream_t stream) {
  const float* x = (const float*)d_in[0];
  const float* ln_g = (const float*)d_in[1];
  const float* ln_b = (const float*)d_in[2];
  const float* w = (const float*)d_in[3];
  const float* bias = (const float*)d_in[4];

  float* out = (float*)d_out;
  float* sparse = out + (size_t)67108864;
  float* coords = sparse + 32768;
  float* sparsity = coords + 512;

  float* ws = (float*)d_ws;
  float* pyr3 = ws;
  float* pyr2 = ws + 65536;
  float* pyr1 = ws + 81920;
  float* pyr0 = ws + 86016;
  int* tokens = (int*)(ws + 87040);
  int* val_id = tokens + BB * 64;

  hipLaunchKernelGGL(pool3_kernel, dim3(BB * CC * 8), dim3(256), 0, stream, x,
                     pyr3);
  hipLaunchKernelGGL(levels_kernel, dim3(BB), dim3(256), 0, stream, pyr3, pyr2,
                     pyr1, pyr0, tokens, val_id, coords, sparsity);
  hipLaunchKernelGGL(proj_kernel, dim3(BB * 32), dim3(256), 0, stream, pyr3,
                     pyr2, pyr1, pyr0, tokens, ln_g, ln_b, w, bias, sparse);
  hipLaunchKernelGGL(fill_kernel, dim3(16384), dim3(256), 0, stream, sparse,
                     val_id, (floatx4*)out);
}